// Round 1
// baseline (820.585 us; speedup 1.0000x reference)
//
#include <hip/hip_runtime.h>
#include <cstdint>
#include <cstddef>

typedef __bf16 bf16;
typedef __bf16 bf16x8 __attribute__((ext_vector_type(8)));
typedef __bf16 bf16x4 __attribute__((ext_vector_type(4)));
typedef float  f32x4  __attribute__((ext_vector_type(4)));

#define WAITV asm volatile("s_waitcnt vmcnt(0)" ::: "memory")

__device__ __forceinline__ void gload16(const void* g, void* l) {
  __builtin_amdgcn_global_load_lds(
      (const __attribute__((address_space(1))) void*)g,
      (__attribute__((address_space(3))) void*)l, 16, 0, 0);
}

// ---------------- convert q/k/v inputs fp32 -> bf16 (3 contiguous tensors) ----------------
__global__ __launch_bounds__(256) void convert_x(
    const float* __restrict__ a, const float* __restrict__ b,
    const float* __restrict__ c, bf16* __restrict__ dst) {
  int i = blockIdx.x * 256 + threadIdx.x;           // float4 group id, 0 .. 3*1048576-1
  const float* src = (i < 1048576) ? a : ((i < 2097152) ? b : c);
  int j = i & 1048575;
  float4 v = ((const float4*)src)[j];
  bf16x4 o;
  o.x = (bf16)v.x; o.y = (bf16)v.y; o.z = (bf16)v.z; o.w = (bf16)v.w;
  ((bf16x4*)dst)[i] = o;
}

// ---------------- transpose 4 weights fp32[512][512] -> bf16 WT[4][n][k] ----------------
__global__ __launch_bounds__(256) void convert_w(
    const float* __restrict__ w0, const float* __restrict__ w1,
    const float* __restrict__ w2, const float* __restrict__ w3,
    bf16* __restrict__ dst) {
  int i = blockIdx.x * 256 + threadIdx.x;           // 0 .. 4*262144-1
  int w = i >> 18, r = i & 262143;
  int kin = r >> 9, n = r & 511;
  const float* W = (w == 0) ? w0 : (w == 1) ? w1 : (w == 2) ? w2 : w3;
  dst[(w << 18) + (n << 9) + kin] = (bf16)W[r];     // coalesced read, scattered 2B write (2MB total)
}

// ---------------- 8192x512x512 bf16 MFMA GEMM, mode-specific epilogue ----------------
#define MODE_Q 0
#define MODE_K 1
#define MODE_V 2
#define MODE_O 3

template <int MODE>
__global__ __launch_bounds__(256, 2) void gemm512(
    const bf16* __restrict__ X, const bf16* __restrict__ WT,
    const float* __restrict__ bias, void* __restrict__ outp, float scale) {
  __shared__ __align__(16) bf16 As[128 * 32];
  __shared__ __align__(16) bf16 Bs[128 * 32];
  const int t = threadIdx.x, wid = t >> 6, lane = t & 63, quad = lane >> 4, l15 = lane & 15;
  const int bm = blockIdx.x, bn = blockIdx.y;
  const int wm = wid & 1, wn = wid >> 1;
  f32x4 acc[4][4] = {};
  const bf16* Ab = X + (size_t)bm * 128 * 512;
  const bf16* Bb = WT + (size_t)bn * 128 * 512;
  for (int kk = 0; kk < 16; ++kk) {
    __syncthreads();
#pragma unroll
    for (int i = 0; i < 2; ++i) {
      int seg = i * 256 + t;
      int row = seg >> 2, off = (seg & 3) << 3;
      gload16(Ab + row * 512 + kk * 32 + off, (char*)As + i * 4096 + wid * 1024);
      gload16(Bb + row * 512 + kk * 32 + off, (char*)Bs + i * 4096 + wid * 1024);
    }
    WAITV;
    __syncthreads();
    bf16x8 af[4], bfr[4];
#pragma unroll
    for (int mi = 0; mi < 4; ++mi)
      af[mi] = *(const bf16x8*)&As[(wm * 64 + mi * 16 + l15) * 32 + quad * 8];
#pragma unroll
    for (int ni = 0; ni < 4; ++ni)
      bfr[ni] = *(const bf16x8*)&Bs[(wn * 64 + ni * 16 + l15) * 32 + quad * 8];
#pragma unroll
    for (int mi = 0; mi < 4; ++mi)
#pragma unroll
      for (int ni = 0; ni < 4; ++ni)
        acc[mi][ni] = __builtin_amdgcn_mfma_f32_16x16x32_bf16(af[mi], bfr[ni], acc[mi][ni], 0, 0, 0);
  }
#pragma unroll
  for (int mi = 0; mi < 4; ++mi) {
#pragma unroll
    for (int ni = 0; ni < 4; ++ni) {
      int C = bn * 128 + wn * 64 + ni * 16 + l15;
      float bia = bias[C];
#pragma unroll
      for (int r = 0; r < 4; ++r) {
        int R = bm * 128 + wm * 64 + mi * 16 + quad * 4 + r;
        float val = acc[mi][ni][r] + bia;
        if (MODE == MODE_O) {
          ((float*)outp)[(size_t)R * 512 + C] = val;
        } else if (MODE == MODE_V) {
          int b = R >> 11, s = R & 2047, h = C >> 6, d = C & 63;
          ((bf16*)outp)[((size_t)((b * 8 + h) * 64 + d)) * 2048 + s] = (bf16)val;
        } else {  // Q or K: [B,H,S,D]
          int b = R >> 11, s = R & 2047, h = C >> 6, d = C & 63;
          ((bf16*)outp)[((size_t)((b * 8 + h) * 2048 + s)) * 64 + d] = (bf16)(val * scale);
        }
      }
    }
  }
}

// ---------------- fused attention: QK^T (2-pass online softmax) + attn write + PV ----------------
// Q,K: [BH][S][D] bf16 (Q pre-scaled by 0.125*log2e); VT: [BH][D][S] bf16.
// attn: fp32 [BH][S][S] (d_out region); ctx: bf16 [B,S,E].
__global__ __launch_bounds__(256, 4) void attn_fused(
    const bf16* __restrict__ Q, const bf16* __restrict__ K,
    const bf16* __restrict__ VT, float* __restrict__ attn,
    bf16* __restrict__ ctx_out) {
  __shared__ __align__(16) bf16 Qs[64 * 64];
  __shared__ __align__(16) bf16 Ks[64 * 64];
  __shared__ __align__(16) bf16 Vs[64 * 64];
  __shared__ __align__(16) bf16 Ps[64 * 72];  // +8 pad: breaks bank conflicts on b16 writes
  const int t = threadIdx.x, wid = t >> 6, lane = t & 63, quad = lane >> 4, l15 = lane & 15;
  const int qt = blockIdx.x, bh = blockIdx.y;
  const bf16* Qg = Q + ((size_t)bh * 2048 + qt * 64) * 64;
  const bf16* Kg = K + (size_t)bh * 2048 * 64;
  const bf16* Vg = VT + (size_t)bh * 64 * 2048;
  float* Ag = attn + ((size_t)bh * 2048 + qt * 64) * 2048;

  // stage Q tile (64x64 bf16 = 8KB)
#pragma unroll
  for (int i = 0; i < 2; ++i) {
    int seg = i * 256 + t;
    gload16(Qg + (seg >> 3) * 64 + (seg & 7) * 8, (char*)Qs + i * 4096 + wid * 1024);
  }
  WAITV;
  __syncthreads();
  bf16x8 aq[2];
#pragma unroll
  for (int ks = 0; ks < 2; ++ks)
    aq[ks] = *(const bf16x8*)&Qs[(wid * 16 + l15) * 64 + ks * 32 + quad * 8];

  float m[4], l[4];
#pragma unroll
  for (int r = 0; r < 4; ++r) { m[r] = -1e30f; l[r] = 0.f; }

  // ---- pass A: running row max / sumexp (base-2 domain) ----
#pragma unroll 1
  for (int kc = 0; kc < 32; ++kc) {
    __syncthreads();
#pragma unroll
    for (int i = 0; i < 2; ++i) {
      int seg = i * 256 + t;
      gload16(Kg + ((size_t)(kc * 64 + (seg >> 3))) * 64 + (seg & 7) * 8,
              (char*)Ks + i * 4096 + wid * 1024);
    }
    WAITV;
    __syncthreads();
    f32x4 c[4];
#pragma unroll
    for (int ni = 0; ni < 4; ++ni) {
      c[ni] = (f32x4){0.f, 0.f, 0.f, 0.f};
#pragma unroll
      for (int ks = 0; ks < 2; ++ks) {
        bf16x8 bk = *(const bf16x8*)&Ks[(ni * 16 + l15) * 64 + ks * 32 + quad * 8];
        c[ni] = __builtin_amdgcn_mfma_f32_16x16x32_bf16(aq[ks], bk, c[ni], 0, 0, 0);
      }
    }
#pragma unroll
    for (int r = 0; r < 4; ++r) {
      float mc = fmaxf(fmaxf(c[0][r], c[1][r]), fmaxf(c[2][r], c[3][r]));
      mc = fmaxf(mc, __shfl_xor(mc, 1));
      mc = fmaxf(mc, __shfl_xor(mc, 2));
      mc = fmaxf(mc, __shfl_xor(mc, 4));
      mc = fmaxf(mc, __shfl_xor(mc, 8));
      float mn = fmaxf(m[r], mc);
      float sum = __builtin_amdgcn_exp2f(c[0][r] - mn) + __builtin_amdgcn_exp2f(c[1][r] - mn) +
                  __builtin_amdgcn_exp2f(c[2][r] - mn) + __builtin_amdgcn_exp2f(c[3][r] - mn);
      sum += __shfl_xor(sum, 1);
      sum += __shfl_xor(sum, 2);
      sum += __shfl_xor(sum, 4);
      sum += __shfl_xor(sum, 8);
      l[r] = l[r] * __builtin_amdgcn_exp2f(m[r] - mn) + sum;
      m[r] = mn;
    }
  }
  float il[4];
#pragma unroll
  for (int r = 0; r < 4; ++r) il[r] = 1.0f / l[r];

  // ---- pass B: recompute scores, normalize, write attn, PV ----
  f32x4 o[4] = {};
#pragma unroll 1
  for (int kc = 0; kc < 32; ++kc) {
    __syncthreads();
#pragma unroll
    for (int i = 0; i < 2; ++i) {
      int seg = i * 256 + t;
      gload16(Kg + ((size_t)(kc * 64 + (seg >> 3))) * 64 + (seg & 7) * 8,
              (char*)Ks + i * 4096 + wid * 1024);
      gload16(Vg + ((size_t)(seg >> 3)) * 2048 + kc * 64 + (seg & 7) * 8,
              (char*)Vs + i * 4096 + wid * 1024);
    }
    WAITV;
    __syncthreads();
    f32x4 c[4];
#pragma unroll
    for (int ni = 0; ni < 4; ++ni) {
      c[ni] = (f32x4){0.f, 0.f, 0.f, 0.f};
#pragma unroll
      for (int ks = 0; ks < 2; ++ks) {
        bf16x8 bk = *(const bf16x8*)&Ks[(ni * 16 + l15) * 64 + ks * 32 + quad * 8];
        c[ni] = __builtin_amdgcn_mfma_f32_16x16x32_bf16(aq[ks], bk, c[ni], 0, 0, 0);
      }
    }
#pragma unroll
    for (int ni = 0; ni < 4; ++ni) {
#pragma unroll
      for (int r = 0; r < 4; ++r) {
        float p = __builtin_amdgcn_exp2f(c[ni][r] - m[r]) * il[r];
        Ag[(size_t)(wid * 16 + quad * 4 + r) * 2048 + kc * 64 + ni * 16 + l15] = p;
        Ps[(wid * 16 + quad * 4 + r) * 72 + ni * 16 + l15] = (bf16)p;
      }
    }
    // P (same-wave LDS round-trip) @ V
    bf16x8 pa[2];
#pragma unroll
    for (int ks = 0; ks < 2; ++ks)
      pa[ks] = *(const bf16x8*)&Ps[(wid * 16 + l15) * 72 + ks * 32 + quad * 8];
#pragma unroll
    for (int ni = 0; ni < 4; ++ni) {
#pragma unroll
      for (int ks = 0; ks < 2; ++ks) {
        bf16x8 bv = *(const bf16x8*)&Vs[(ni * 16 + l15) * 64 + ks * 32 + quad * 8];
        o[ni] = __builtin_amdgcn_mfma_f32_16x16x32_bf16(pa[ks], bv, o[ni], 0, 0, 0);
      }
    }
  }

  // epilogue: context -> ws as [B,S,E] bf16
  const int b = bh >> 3, h = bh & 7;
#pragma unroll
  for (int ni = 0; ni < 4; ++ni) {
#pragma unroll
    for (int r = 0; r < 4; ++r) {
      int s = qt * 64 + wid * 16 + quad * 4 + r;
      ctx_out[((size_t)(b * 2048 + s)) * 512 + h * 64 + ni * 16 + l15] = (bf16)o[ni][r];
    }
  }
}

extern "C" void kernel_launch(void* const* d_in, const int* in_sizes, int n_in,
                              void* d_out, int out_size, void* d_ws, size_t ws_size,
                              hipStream_t stream) {
  const float* query = (const float*)d_in[0];
  const float* key   = (const float*)d_in[1];
  const float* value = (const float*)d_in[2];
  const float* Wq = (const float*)d_in[3];
  const float* bq = (const float*)d_in[4];
  const float* Wk = (const float*)d_in[5];
  const float* bk = (const float*)d_in[6];
  const float* Wv = (const float*)d_in[7];
  const float* bv = (const float*)d_in[8];
  const float* Wo = (const float*)d_in[9];
  const float* bo = (const float*)d_in[10];

  float* out  = (float*)d_out;                 // [4,2048,512] fp32
  float* attn = out + (size_t)4 * 2048 * 512;  // [4,8,2048,2048] fp32

  // workspace layout (50 MiB total):
  //   0        : Xq,Xk,Xv bf16 (3 x 8,388,608 B)  [ctx aliases Xq after proj GEMMs]
  //   25165824 : WqT,WkT,WvT,WoT bf16 (4 x 524,288 B)
  //   27262976 : qbuf / 35651584 : kbuf / 44040192 : vT buf (bf16)
  char* ws = (char*)d_ws;
  bf16* Xqkv = (bf16*)ws;
  bf16* WT   = (bf16*)(ws + 25165824);
  bf16* qb   = (bf16*)(ws + 27262976);
  bf16* kb   = (bf16*)(ws + 35651584);
  bf16* vtb  = (bf16*)(ws + 44040192);
  bf16* ctx  = (bf16*)ws;  // alias: Xq dead after Q projection

  convert_x<<<12288, 256, 0, stream>>>(query, key, value, Xqkv);
  convert_w<<<4096, 256, 0, stream>>>(Wq, Wk, Wv, Wo, WT);

  dim3 g(64, 4);
  // fold (1/sqrt(64)) * log2(e) into Q so softmax runs in base-2 with raw v_exp_f32
  const float QSCALE = 0.18033688011112042592f;
  gemm512<MODE_Q><<<g, 256, 0, stream>>>(Xqkv,           WT,          bq, qb,  QSCALE);
  gemm512<MODE_K><<<g, 256, 0, stream>>>(Xqkv + 4194304, WT + 262144, bk, kb,  1.0f);
  gemm512<MODE_V><<<g, 256, 0, stream>>>(Xqkv + 8388608, WT + 524288, bv, vtb, 1.0f);

  attn_fused<<<dim3(32, 32), 256, 0, stream>>>(qb, kb, vtb, attn, ctx);

  gemm512<MODE_O><<<g, 256, 0, stream>>>(ctx, WT + 786432, bo, out, 1.0f);
}